// Round 4
// baseline (47.909 us; speedup 1.0000x reference)
//
#include <hip/hip_runtime.h>

// Chamfer loss: X, Y f32 [8, 3, 4096] -> scalar mean of (d1+d2)/2.
// dir 0: queries = X, targets = Y; dir 1: queries = Y, targets = X.
//
// main: Q=8 queries/thread, TS=32 target slices -> 1024 blocks (4/CU).
//   inner loop computes d' = rt - 2 q.t (3 FMA/distance, ra hoisted out);
//   cross-slice combine via atomicMin on uint bits of (ra + min d') >= 0.
// reduce: one 1024-thread block sums the 65536 per-query minima (fixed
//   order -> deterministic) and scales.

constexpr int NPTS = 4096;
constexpr int NB   = 8;
constexpr int TPB  = 256;
constexpr int Q    = 8;                    // queries per thread
constexpr int QT   = NPTS / (TPB * Q);     // 2 query tiles per (dir,b)
constexpr int TS   = 32;                   // target slices
constexpr int TGT  = NPTS / TS;            // 128 targets per slice
constexpr int MAIN_BLOCKS = 2 * NB * QT * TS;  // 1024
constexpr int NQ_TOTAL    = 2 * NB * NPTS;     // 65536 query slots

__global__ __launch_bounds__(TPB, 4) void chamfer_main(
    const float* __restrict__ X, const float* __restrict__ Y,
    unsigned* __restrict__ minbits)
{
    __shared__ float4 s[TGT];   // 2 KB: (tx, ty, tz, ||t||^2)

    const int bid = blockIdx.x;
    const int ts  = bid & (TS - 1);
    int rest      = bid >> 5;
    const int qt  = rest & (QT - 1);
    rest >>= 1;
    const int b   = rest & (NB - 1);
    const int dir = rest >> 3;

    const float* __restrict__ Qb = (dir ? Y : X) + b * 3 * NPTS;
    const float* __restrict__ Tb = (dir ? X : Y) + b * 3 * NPTS;

    // Stage this block's target slice (TGT=128 < TPB).
    if (threadIdx.x < TGT) {
        const int i = ts * TGT + threadIdx.x;
        float tx = Tb[i];
        float ty = Tb[NPTS + i];
        float tz = Tb[2 * NPTS + i];
        s[threadIdx.x] = make_float4(tx, ty, tz,
                                     fmaf(tx, tx, fmaf(ty, ty, tz * tz)));
    }
    __syncthreads();

    // Load Q=8 queries per thread (stride TPB -> coalesced).
    float nx[Q], ny[Q], nz[Q], ra[Q], mn[Q];
    const int qbase = qt * (TPB * Q) + threadIdx.x;
    #pragma unroll
    for (int k = 0; k < Q; ++k) {
        const int q = qbase + k * TPB;
        float qx = Qb[q];
        float qy = Qb[NPTS + q];
        float qz = Qb[2 * NPTS + q];
        ra[k] = fmaf(qx, qx, fmaf(qy, qy, qz * qz));
        nx[k] = -2.0f * qx;
        ny[k] = -2.0f * qy;
        nz[k] = -2.0f * qz;
        mn[k] = 3.4e38f;
    }

    // d' = rt - 2 q.t : 3 FMA per distance; 2 v_min3 per 4 targets.
    // min_t(||q-t||^2) = ra + min_t(d').
    for (int m = 0; m < TGT; m += 4) {
        float4 p0 = s[m + 0];
        float4 p1 = s[m + 1];
        float4 p2 = s[m + 2];
        float4 p3 = s[m + 3];
        #pragma unroll
        for (int k = 0; k < Q; ++k) {
            float d0 = fmaf(nx[k], p0.x, fmaf(ny[k], p0.y, fmaf(nz[k], p0.z, p0.w)));
            float d1 = fmaf(nx[k], p1.x, fmaf(ny[k], p1.y, fmaf(nz[k], p1.z, p1.w)));
            float d2 = fmaf(nx[k], p2.x, fmaf(ny[k], p2.y, fmaf(nz[k], p2.z, p2.w)));
            float d3 = fmaf(nx[k], p3.x, fmaf(ny[k], p3.y, fmaf(nz[k], p3.z, p3.w)));
            mn[k] = fminf(mn[k], fminf(d0, d1));   // -> v_min3
            mn[k] = fminf(mn[k], fminf(d2, d3));   // -> v_min3
        }
    }

    // Cross-slice combine: atomicMin on uint bits (valid for floats >= 0;
    // order-independent -> deterministic). Coalesced across lanes.
    unsigned* mb = minbits + (dir * NB + b) * NPTS + qbase;
    #pragma unroll
    for (int k = 0; k < Q; ++k) {
        float v = fmaxf(ra[k] + mn[k], 0.0f);
        atomicMin(&mb[k * TPB], __float_as_uint(v));
    }
}

__global__ __launch_bounds__(1024, 1) void chamfer_reduce(
    const unsigned* __restrict__ minbits, float* __restrict__ out)
{
    __shared__ float wsum[16];
    // 65536 elems, 1024 threads, 64 per thread, stride-1024 (coalesced).
    float acc = 0.0f;
    #pragma unroll
    for (int i = 0; i < NQ_TOTAL / 1024; ++i) {
        acc += __uint_as_float(minbits[i * 1024 + threadIdx.x]);
    }
    #pragma unroll
    for (int off = 32; off > 0; off >>= 1) acc += __shfl_down(acc, off);
    if ((threadIdx.x & 63) == 0) wsum[threadIdx.x >> 6] = acc;
    __syncthreads();
    if (threadIdx.x == 0) {
        float t = 0.0f;
        #pragma unroll
        for (int i = 0; i < 16; ++i) t += wsum[i];
        // mean over [B, N] of (d1+d2)/2  ->  total / (2*8*4096)
        out[0] = t * (1.0f / (2.0f * NB * NPTS));
    }
}

extern "C" void kernel_launch(void* const* d_in, const int* in_sizes, int n_in,
                              void* d_out, int out_size, void* d_ws, size_t ws_size,
                              hipStream_t stream) {
    const float* X = (const float*)d_in[0];
    const float* Y = (const float*)d_in[1];

    unsigned* minbits = (unsigned*)d_ws;   // 65536 u32 = 256 KB
    float*    out     = (float*)d_out;

    // 0x7F7F7F7F as uint > any non-negative distance's bits (~3.39e38 f32).
    hipMemsetAsync(minbits, 0x7F, NQ_TOTAL * sizeof(unsigned), stream);
    chamfer_main<<<MAIN_BLOCKS, TPB, 0, stream>>>(X, Y, minbits);
    chamfer_reduce<<<1, 1024, 0, stream>>>(minbits, out);
}

// Round 5
// 35.301 us; speedup vs baseline: 1.3571x; 1.3571x over previous
//
#include <hip/hip_runtime.h>

// Chamfer loss: X, Y f32 [8, 3, 4096] -> scalar mean of (d1+d2)/2.
// dir 0: queries = X, targets = Y; dir 1: queries = Y, targets = X.
//
// main: Q=16 queries/thread (full cloud per block), TS=32 target slices
//   -> 512 blocks (2/CU). Inner loop d' = rt - 2 q.t (3 FMA/distance);
//   per-slice min stored plain to minslice[ts][qslot].
// reduce: 64 blocks float4-min over 32 slices + partial sums; last block
//   (int-counter handshake) sums 64 partials in fixed order -> scalar.

constexpr int NPTS = 4096;
constexpr int NB   = 8;
constexpr int TPB  = 256;
constexpr int Q    = 16;                   // queries per thread (full cloud/block)
constexpr int TS   = 32;                   // target slices
constexpr int TGT  = NPTS / TS;            // 128 targets per slice
constexpr int MAIN_BLOCKS = 2 * NB * TS;   // 512
constexpr int NQ_TOTAL    = 2 * NB * NPTS; // 65536 query slots
constexpr int RED_BLOCKS  = 64;

__global__ __launch_bounds__(TPB, 2) void chamfer_main(
    const float* __restrict__ X, const float* __restrict__ Y,
    float* __restrict__ minslice, unsigned* __restrict__ counter)
{
    __shared__ float4 s[TGT];   // 2 KB: (tx, ty, tz, ||t||^2)

    const int bid = blockIdx.x;
    const int ts  = bid & (TS - 1);
    const int b   = (bid >> 5) & (NB - 1);
    const int dir = bid >> 8;

    if (bid == 0 && threadIdx.x == 0) *counter = 0;  // for reduce handshake

    const float* __restrict__ Qb = (dir ? Y : X) + b * 3 * NPTS;
    const float* __restrict__ Tb = (dir ? X : Y) + b * 3 * NPTS;

    // Stage this block's target slice (TGT=128 < TPB).
    if (threadIdx.x < TGT) {
        const int i = ts * TGT + threadIdx.x;
        float tx = Tb[i];
        float ty = Tb[NPTS + i];
        float tz = Tb[2 * NPTS + i];
        s[threadIdx.x] = make_float4(tx, ty, tz,
                                     fmaf(tx, tx, fmaf(ty, ty, tz * tz)));
    }
    __syncthreads();

    // Load Q=16 queries per thread (stride TPB -> coalesced).
    float nx[Q], ny[Q], nz[Q], ra[Q], mn[Q];
    #pragma unroll
    for (int k = 0; k < Q; ++k) {
        const int q = threadIdx.x + k * TPB;
        float qx = Qb[q];
        float qy = Qb[NPTS + q];
        float qz = Qb[2 * NPTS + q];
        ra[k] = fmaf(qx, qx, fmaf(qy, qy, qz * qz));
        nx[k] = -2.0f * qx;
        ny[k] = -2.0f * qy;
        nz[k] = -2.0f * qz;
        mn[k] = 3.4e38f;
    }

    // d' = rt - 2 q.t : 3 FMA/distance; 2 v_min3 per 4 targets.
    // min_t(||q-t||^2) = ra + min_t(d').
    for (int m = 0; m < TGT; m += 4) {
        float4 p0 = s[m + 0];
        float4 p1 = s[m + 1];
        float4 p2 = s[m + 2];
        float4 p3 = s[m + 3];
        #pragma unroll
        for (int k = 0; k < Q; ++k) {
            float d0 = fmaf(nx[k], p0.x, fmaf(ny[k], p0.y, fmaf(nz[k], p0.z, p0.w)));
            float d1 = fmaf(nx[k], p1.x, fmaf(ny[k], p1.y, fmaf(nz[k], p1.z, p1.w)));
            float d2 = fmaf(nx[k], p2.x, fmaf(ny[k], p2.y, fmaf(nz[k], p2.z, p2.w)));
            float d3 = fmaf(nx[k], p3.x, fmaf(ny[k], p3.y, fmaf(nz[k], p3.z, p3.w)));
            mn[k] = fminf(mn[k], fminf(d0, d1));   // -> v_min3
            mn[k] = fminf(mn[k], fminf(d2, d3));   // -> v_min3
        }
    }

    // Per-slice result. Coalesced stores, disjoint per block.
    float* out = minslice + ts * NQ_TOTAL + (dir * NB + b) * NPTS + threadIdx.x;
    #pragma unroll
    for (int k = 0; k < Q; ++k) {
        out[k * TPB] = ra[k] + mn[k];
    }
}

__global__ __launch_bounds__(TPB) void chamfer_reduce(
    const float4* __restrict__ ms4,   // minslice viewed as [TS][NQ_TOTAL/4] float4
    float* __restrict__ partials, unsigned* __restrict__ counter,
    float* __restrict__ out)
{
    __shared__ float wsum[TPB / 64];
    __shared__ int   lastFlag;

    const int idx = blockIdx.x * TPB + threadIdx.x;   // 0..16383 float4 slots
    float4 m = ms4[idx];
    #pragma unroll
    for (int ts = 1; ts < TS; ++ts) {
        float4 v = ms4[ts * (NQ_TOTAL / 4) + idx];
        m.x = fminf(m.x, v.x);
        m.y = fminf(m.y, v.y);
        m.z = fminf(m.z, v.z);
        m.w = fminf(m.w, v.w);
    }
    float v = (m.x + m.y) + (m.z + m.w);
    #pragma unroll
    for (int off = 32; off > 0; off >>= 1) v += __shfl_down(v, off);
    if ((threadIdx.x & 63) == 0) wsum[threadIdx.x >> 6] = v;
    __syncthreads();
    if (threadIdx.x == 0) {
        float acc = 0.0f;
        #pragma unroll
        for (int i = 0; i < TPB / 64; ++i) acc += wsum[i];
        partials[blockIdx.x] = acc;
        __threadfence();                         // publish partial
        unsigned old = atomicAdd(counter, 1u);   // device-scope
        lastFlag = (old == RED_BLOCKS - 1);
    }
    __syncthreads();

    if (lastFlag) {
        __threadfence();                         // acquire partials
        if (threadIdx.x < 64) {
            float p = partials[threadIdx.x];
            #pragma unroll
            for (int off = 32; off > 0; off >>= 1) p += __shfl_down(p, off);
            if (threadIdx.x == 0) {
                // mean over [B, N] of (d1+d2)/2 -> total / (2*8*4096)
                out[0] = p * (1.0f / (2.0f * NB * NPTS));
            }
        }
    }
}

extern "C" void kernel_launch(void* const* d_in, const int* in_sizes, int n_in,
                              void* d_out, int out_size, void* d_ws, size_t ws_size,
                              hipStream_t stream) {
    const float* X = (const float*)d_in[0];
    const float* Y = (const float*)d_in[1];

    float*    minslice = (float*)d_ws;                        // 32*65536 f32 = 8 MB
    float*    partials = (float*)((char*)d_ws + (size_t)TS * NQ_TOTAL * sizeof(float));
    unsigned* counter  = (unsigned*)(partials + RED_BLOCKS);
    float*    out      = (float*)d_out;

    chamfer_main<<<MAIN_BLOCKS, TPB, 0, stream>>>(X, Y, minslice, counter);
    chamfer_reduce<<<RED_BLOCKS, TPB, 0, stream>>>(
        (const float4*)minslice, partials, counter, out);
}